// Round 1
// baseline (231.819 us; speedup 1.0000x reference)
//
#include <hip/hip_runtime.h>

// LIF neuron scan: x[T,B,D] f32, v0[D] f32 -> spikes[T,B,D] f32.
// T=512, B=64, D=1024. One thread per (b,d) chain; sequential in T.
// tau=0.5 (exact mul), threshold=1.0, v_reset=0.0.

constexpr int T_STEPS = 512;
constexpr int B_DIM   = 64;
constexpr int D_DIM   = 1024;
constexpr int N_CHAIN = B_DIM * D_DIM;   // 65536 independent chains

__global__ __launch_bounds__(256)
void lif_scan_kernel(const float* __restrict__ x,
                     const float* __restrict__ v0,
                     float* __restrict__ out) {
    const int tid = blockIdx.x * blockDim.x + threadIdx.x;  // chain id = b*D + d
    const int d   = tid & (D_DIM - 1);

    float v = v0[d];

    const float* xp = x   + tid;
    float*       op = out + tid;

    // Each timestep: whole-wave contiguous 256B read + 256B write (coalesced).
    // Unroll so ~16 independent global loads stay in flight per wave.
#pragma unroll 16
    for (int t = 0; t < T_STEPS; ++t) {
        const float xt = xp[(size_t)t * N_CHAIN];
        v = v * 0.5f + xt;                 // exact mul by 0.5 -> matches ref bit-for-bit
        const bool s = (v >= 1.0f);
        op[(size_t)t * N_CHAIN] = s ? 1.0f : 0.0f;
        v = s ? 0.0f : v;                  // reset
    }
}

extern "C" void kernel_launch(void* const* d_in, const int* in_sizes, int n_in,
                              void* d_out, int out_size, void* d_ws, size_t ws_size,
                              hipStream_t stream) {
    const float* x   = (const float*)d_in[0];
    const float* v0  = (const float*)d_in[1];
    float*       out = (float*)d_out;

    dim3 block(256);
    dim3 grid(N_CHAIN / 256);   // 256 blocks -> 1 block/CU on 256 CUs, 4 waves/CU
    hipLaunchKernelGGL(lif_scan_kernel, grid, block, 0, stream, x, v0, out);
}

// Round 4
// 226.748 us; speedup vs baseline: 1.0224x; 1.0224x over previous
//
#include <hip/hip_runtime.h>

// LIF neuron scan: x[T,B,D] f32, v0[D] f32 -> spikes[T,B,D] f32.
// T=512, B=64, D=1024. One thread per (b,d) chain; sequential in T.
// tau=0.5 (exact mul), threshold=1.0, v_reset=0.0.
//
// R1 analysis: 65,536 chains = 1024 waves = 1 wave/SIMD. Latency hiding must
// come from ILP. Naive unroll left only ~2 loads in flight (VGPR=28, 2.5 TB/s).
// R2: explicit ping-pong register prefetch of U=16 timesteps so ~16 loads/wave
// stay outstanding while the serial v-chain consumes the previous block.
// (R2/R3 benches never ran — broker timeouts; resubmitting unchanged.)

constexpr int T_STEPS = 512;
constexpr int B_DIM   = 64;
constexpr int D_DIM   = 1024;
constexpr int N_CHAIN = B_DIM * D_DIM;   // 65536 independent chains
constexpr int U       = 16;              // prefetch depth (timesteps per block)

__global__ __launch_bounds__(256)
void lif_scan_kernel(const float* __restrict__ x,
                     const float* __restrict__ v0,
                     float* __restrict__ out) {
    const int tid = blockIdx.x * blockDim.x + threadIdx.x;  // chain id = b*D + d
    const int d   = tid & (D_DIM - 1);

    float v = v0[d];

    const float* xp = x   + tid;
    float*       op = out + tid;

    float bufA[U], bufB[U];   // static-indexed only (no scratch spill)

    // Prologue: load block 0 into A.
#pragma unroll
    for (int u = 0; u < U; ++u)
        bufA[u] = xp[(size_t)u * N_CHAIN];

    // Steady state: 512 / (2*16) = 16 double-block iterations.
    for (int t0 = 0; t0 < T_STEPS; t0 += 2 * U) {
        // Prefetch B = block [t0+U, t0+2U)  (t0+U <= 496 < 512, always in bounds)
#pragma unroll
        for (int u = 0; u < U; ++u)
            bufB[u] = xp[(size_t)(t0 + U + u) * N_CHAIN];

        // Consume block A at t0 (serial v-chain; loads for B in flight above).
#pragma unroll
        for (int u = 0; u < U; ++u) {
            v = v * 0.5f + bufA[u];            // exact: tau = 0.5
            const bool s = (v >= 1.0f);
            __builtin_nontemporal_store(s ? 1.0f : 0.0f,
                                        op + (size_t)(t0 + u) * N_CHAIN);
            v = s ? 0.0f : v;
        }

        // Prefetch A = block [t0+2U, t0+3U)  (skip on final iteration)
        const int tn = t0 + 2 * U;
        if (tn < T_STEPS) {
#pragma unroll
            for (int u = 0; u < U; ++u)
                bufA[u] = xp[(size_t)(tn + u) * N_CHAIN];
        }

        // Consume block B at t0+U.
#pragma unroll
        for (int u = 0; u < U; ++u) {
            v = v * 0.5f + bufB[u];
            const bool s = (v >= 1.0f);
            __builtin_nontemporal_store(s ? 1.0f : 0.0f,
                                        op + (size_t)(t0 + U + u) * N_CHAIN);
            v = s ? 0.0f : v;
        }
    }
}

extern "C" void kernel_launch(void* const* d_in, const int* in_sizes, int n_in,
                              void* d_out, int out_size, void* d_ws, size_t ws_size,
                              hipStream_t stream) {
    const float* x   = (const float*)d_in[0];
    const float* v0  = (const float*)d_in[1];
    float*       out = (float*)d_out;

    dim3 block(256);
    dim3 grid(N_CHAIN / 256);   // 256 blocks -> 1 block/CU, 4 waves/CU (1/SIMD)
    hipLaunchKernelGGL(lif_scan_kernel, grid, block, 0, stream, x, v0, out);
}

// Round 6
// 226.547 us; speedup vs baseline: 1.0233x; 1.0009x over previous
//
#include <hip/hip_runtime.h>

// LIF neuron scan: x[T,B,D] f32, v0[D] f32 -> spikes[T,B,D] f32.
// T=512, B=64, D=1024. One thread per (b,d) chain; sequential in T.
// tau=0.5 (exact mul), threshold=1.0, v_reset=0.0.
//
// R1: naive unroll -> 2.5 TB/s, VGPR=28: scheduler kept ~2 loads in flight.
// R4: ping-pong prefetch landed at only ~77us (inferred) -> scheduler sank
//     the prefetch loads back between uses (nothing pinned issue order).
// R5: triple-buffer (prefetch distance 2 blocks ~= 700+ cyc > HBM latency)
//     + __builtin_amdgcn_sched_barrier(0) pinning every burst boundary so
//     the backend CANNOT re-serialize the loads. ~48 loads/wave outstanding.
// (R5 bench never ran — broker timeout; resubmitting unchanged.)

constexpr int T_STEPS = 512;
constexpr int B_DIM   = 64;
constexpr int D_DIM   = 1024;
constexpr int N_CHAIN = B_DIM * D_DIM;   // 65536 independent chains
constexpr int U       = 16;              // timesteps per block
constexpr int NB      = T_STEPS / U;     // 32 blocks

__global__ __launch_bounds__(256)
void lif_scan_kernel(const float* __restrict__ x,
                     const float* __restrict__ v0,
                     float* __restrict__ out) {
    const int tid = blockIdx.x * blockDim.x + threadIdx.x;  // chain id = b*D + d
    const int d   = tid & (D_DIM - 1);

    float v = v0[d];

    const float* xp = x   + tid;
    float*       op = out + tid;

    float b0[U], b1[U], b2[U];   // static-indexed only (no scratch)

    // Issue a 16-load burst, then pin it: scheduler may not move anything
    // across the sched_barrier, so all 16 loads are in flight before the
    // serial chain that follows.
#define LOADB(BUF, BLK)                                                     \
    _Pragma("unroll")                                                       \
    for (int u = 0; u < U; ++u)                                             \
        BUF[u] = xp[(size_t)((BLK) * U + u) * N_CHAIN];                     \
    __builtin_amdgcn_sched_barrier(0);

    // Serial LIF chain over one block + nontemporal spike stores (spikes are
    // write-once: keep them out of L3 so x stays resident).
#define CONSB(BUF, BLK)                                                     \
    _Pragma("unroll")                                                       \
    for (int u = 0; u < U; ++u) {                                           \
        v = v * 0.5f + BUF[u];            /* exact: tau = 0.5 */            \
        const bool s = (v >= 1.0f);                                         \
        __builtin_nontemporal_store(s ? 1.0f : 0.0f,                        \
                                    op + (size_t)((BLK) * U + u) * N_CHAIN);\
        v = s ? 0.0f : v;                                                   \
    }                                                                       \
    __builtin_amdgcn_sched_barrier(0);

    // Prologue: blocks 0,1 in flight.
    LOADB(b0, 0)
    LOADB(b1, 1)

    // Steady state: consume block c while blocks c+1, c+2 are in flight.
    // j = 0..9 consumes blocks 0..29, loads up to block 31 (never OOB).
    for (int j = 0; j < 10; ++j) {
        const int c = 3 * j;
        LOADB(b2, c + 2)
        CONSB(b0, c)
        LOADB(b0, c + 3)
        CONSB(b1, c + 1)
        LOADB(b1, c + 4)
        CONSB(b2, c + 2)
    }

    // Epilogue: blocks 30 (in b0) and 31 (in b1) were loaded at j=9.
    CONSB(b0, 30)
    CONSB(b1, 31)

#undef LOADB
#undef CONSB
}

extern "C" void kernel_launch(void* const* d_in, const int* in_sizes, int n_in,
                              void* d_out, int out_size, void* d_ws, size_t ws_size,
                              hipStream_t stream) {
    const float* x   = (const float*)d_in[0];
    const float* v0  = (const float*)d_in[1];
    float*       out = (float*)d_out;

    dim3 block(256);
    dim3 grid(N_CHAIN / 256);   // 256 blocks -> 1 block/CU, 4 waves/CU (1/SIMD)
    hipLaunchKernelGGL(lif_scan_kernel, grid, block, 0, stream, x, v0, out);
}